// Round 3
// baseline (3399.726 us; speedup 1.0000x reference)
//
#include <hip/hip_runtime.h>
#include <hip/hip_bf16.h>

#define N_USERS 70000
#define N_ITEMS 30000
#define N_NODES 100000
#define RD 192      // R*D
#define EE 1600000

// output element offsets (dtype-independent)
#define OFF_U    0
#define OFF_I    13440000
#define OFF_IZ   19200000   // zero row (item index 30000)
#define OFF_RELA 19200192
#define OFF_S1   19200384
#define OFF_S2   19270384

typedef __hip_bfloat16 bf16;

__device__ __forceinline__ float b2f(bf16 v) { return __bfloat162float(v); }

// dtype-adaptive IO: f32 -> fp32 arrays, else bf16 arrays
__device__ __forceinline__ float loadf(const void* p, int i, bool f32) {
  return f32 ? ((const float*)p)[i] : b2f(((const bf16*)p)[i]);
}
__device__ __forceinline__ void storef(void* p, int i, float v, bool f32) {
  if (f32) ((float*)p)[i] = v;
  else ((bf16*)p)[i] = __float2bfloat16(v);
}

__device__ __forceinline__ float wave_sum(float v) {
#pragma unroll
  for (int off = 32; off >= 1; off >>= 1) v += __shfl_xor(v, off, 64);
  return v;
}

// Detect input dtype. bf16 N(0,0.05): every u16 has exponent <= ~124.
// fp32: odd u16s are random mantissa bits -> ~50% have exp >= 127.
__global__ void detect_kernel(const unsigned short* __restrict__ ue,
                              int* __restrict__ flag) {
  __shared__ int s;
  int t = threadIdx.x;
  if (t == 0) s = 0;
  __syncthreads();
  int big = 0;
  for (int j = t; j < 8192; j += 256) {
    int e = (ue[j] >> 7) & 0xFF;
    if (e >= 127) big = 1;
  }
  if (big) atomicOr(&s, 1);
  __syncthreads();
  if (t == 0) *flag = s;
}

__global__ void zero_row_kernel(void* out, const int* __restrict__ flag) {
  bool f32 = *flag != 0;
  storef(out, OFF_IZ + (int)threadIdx.x, 0.f, f32);  // 192 threads
}

// rela chain: rela0=rel_emb, rela1=rela0@W_rel[0], rela2=rela1@W_rel[1]
__global__ void rela_kernel(const void* __restrict__ rel_emb,
                            const void* __restrict__ W_rel,
                            const int* __restrict__ flag,
                            float* __restrict__ rela_f, void* out) {
  bool f32 = *flag != 0;
  __shared__ float r0s[192], r1s[192];
  int t = threadIdx.x;            // 192 threads
  int i = t >> 6, d = t & 63;
  float r0 = loadf(rel_emb, t, f32);
  r0s[t] = r0;
  __syncthreads();
  float acc = 0.f;
  for (int k = 0; k < 64; ++k)
    acc += r0s[i * 64 + k] * loadf(W_rel, k * 64 + d, f32);
  r1s[t] = acc;
  __syncthreads();
  float acc2 = 0.f;
  for (int k = 0; k < 64; ++k)
    acc2 += r1s[i * 64 + k] * loadf(W_rel, 4096 + k * 64 + d, f32);
  rela_f[t] = r0;
  rela_f[192 + t] = acc;
  rela_f[384 + t] = acc2;
  storef(out, OFF_RELA + t, (r0 + acc + acc2) * (1.f / 3.f), f32);
}

__global__ __launch_bounds__(256) void init_kernel(
    const void* __restrict__ user_emb, const void* __restrict__ item_emb,
    const int* __restrict__ flag, bf16* __restrict__ ego,
    float* __restrict__ all_emb) {
  bool f32 = *flag != 0;
  int idx = blockIdx.x * 256 + threadIdx.x;
  if (idx >= N_NODES * RD) return;
  int n = idx / RD;
  int rd = idx - n * RD;
  int d = rd & 63;
  float v = (n < N_USERS) ? loadf(user_emb, n * 64 + d, f32)
                          : loadf(item_emb, (n - N_USERS) * 64 + d, f32);
  ego[idx] = __float2bfloat16(v);
  all_emb[idx] = v;
}

// one wave per edge; lane = dim
__global__ __launch_bounds__(256) void scatter_kernel(
    const bf16* __restrict__ ego, const void* __restrict__ vals,
    const int* __restrict__ rows, const int* __restrict__ cols,
    const int* __restrict__ flag, float* __restrict__ prop) {
  bool f32 = *flag != 0;
  int i = blockIdx.y;
  int e = blockIdx.x * 4 + (threadIdx.x >> 6);
  int lane = threadIdx.x & 63;
  int idx = i * EE + e;
  int r = rows[idx];
  int c = cols[idx];
  float v = loadf(vals, idx, f32);
  float msg = b2f(ego[c * RD + i * 64 + lane]) * v;
  atomicAdd(prop + r * RD + i * 64 + lane, msg);
}

__device__ __forceinline__ float attn_row(float a, float b, float c,
                                          float e0, float e1, float e2) {
  float m = fmaxf(a, fmaxf(b, c));
  float w0 = __expf(a - m), w1 = __expf(b - m), w2 = __expf(c - m);
  float inv = 1.f / (w0 + w1 + w2);
  return (w0 * e0 + w1 * e1 + w2 * e2) * inv;
}

// 32 nodes per block. est = leaky_relu((prop*rela)@Wgc); per-node 3x3 attn;
// writes new ego (bf16) and all_emb += ego. wgc_off = element offset of layer
__global__ __launch_bounds__(256) void transform_attn_kernel(
    const float* __restrict__ prop, const float* __restrict__ rela_k,
    const void* __restrict__ Wgc, int wgc_off, const int* __restrict__ flag,
    bf16* __restrict__ ego, float* __restrict__ all_emb) {
  bool f32 = *flag != 0;
  __shared__ float Ws[4096];
  __shared__ float est_s[32 * RD];
  int t = threadIdx.x, lane = t & 63, wave = t >> 6;
  for (int j = t; j < 4096; j += 256) Ws[j] = loadf(Wgc, wgc_off + j, f32);
  float rel0 = rela_k[lane], rel1 = rela_k[64 + lane], rel2 = rela_k[128 + lane];
  __syncthreads();
  int n0 = blockIdx.x * 32;
#pragma unroll
  for (int i = 0; i < 3; ++i) {
    float rel = (i == 0) ? rel0 : ((i == 1) ? rel1 : rel2);
    for (int nl = wave; nl < 32; nl += 4) {
      int n = n0 + nl;
      float x = prop[n * RD + i * 64 + lane] * rel;
      float acc = 0.f;
#pragma unroll
      for (int d = 0; d < 64; ++d)
        acc += __shfl(x, d, 64) * Ws[d * 64 + lane];
      acc = acc > 0.f ? acc : 0.01f * acc;
      est_s[nl * RD + i * 64 + lane] = acc;
    }
  }
  __syncthreads();
  const float sc = 0.088388347648318447f;  // 1/sqrt(128)
  for (int jj = 0; jj < 8; ++jj) {
    int nl = wave * 8 + jj;
    int n = n0 + nl;
    float e0 = est_s[nl * RD + lane];
    float e1 = est_s[nl * RD + 64 + lane];
    float e2 = est_s[nl * RD + 128 + lane];
    float s00 = wave_sum(e0 * e0);
    float s01 = wave_sum(e0 * e1);
    float s02 = wave_sum(e0 * e2);
    float s11 = wave_sum(e1 * e1);
    float s12 = wave_sum(e1 * e2);
    float s22 = wave_sum(e2 * e2);
    float o0 = attn_row(s00 * sc, s01 * sc, s02 * sc, e0, e1, e2);
    float o1 = attn_row(s01 * sc, s11 * sc, s12 * sc, e0, e1, e2);
    float o2 = attn_row(s02 * sc, s12 * sc, s22 * sc, e0, e1, e2);
    int base = n * RD + lane;
    ego[base] = __float2bfloat16(o0);
    ego[base + 64] = __float2bfloat16(o1);
    ego[base + 128] = __float2bfloat16(o2);
    all_emb[base] += o0;
    all_emb[base + 64] += o1;
    all_emb[base + 128] += o2;
  }
}

// final attention (row 2 only) + outputs; users also do GRU matvecs + scores
__global__ __launch_bounds__(256) void final_kernel(
    const float* __restrict__ all_emb, const void* __restrict__ gru_w,
    const void* __restrict__ gru_b, const void* __restrict__ tra,
    const int* __restrict__ flag, void* out) {
  bool f32 = *flag != 0;
  __shared__ float Wg[3 * 4096];
  __shared__ float bs[192];
  __shared__ float ts[256];
  int t = threadIdx.x, lane = t & 63, wave = t >> 6;
  for (int j = t; j < 12288; j += 256) Wg[j] = loadf(gru_w, j, f32);
  if (t < 192) bs[t] = loadf(gru_b, t, f32);
  ts[t] = loadf(tra, t, f32);
  __syncthreads();
  int n0 = blockIdx.x * 64 + wave * 16;
  for (int jj = 0; jj < 16; ++jj) {
    int n = n0 + jj;
    if (n >= N_NODES) break;
    float a0 = all_emb[n * RD + lane];
    float a1 = all_emb[n * RD + 64 + lane];
    float a2 = all_emb[n * RD + 128 + lane];
    float s20 = wave_sum(a2 * a0);
    float s21 = wave_sum(a2 * a1);
    float s22 = wave_sum(a2 * a2);
    float mid2 = attn_row(s20, s21, s22, a0, a1, a2);
    float f0 = a0 * (1.f / 3.f), f1 = a1 * (1.f / 3.f), f2 = mid2 * (1.f / 3.f);
    if (n < N_USERS) {
      int ob = OFF_U + n * RD + lane;
      storef(out, ob, f0, f32);
      storef(out, ob + 64, f1, f32);
      storef(out, ob + 128, f2, f32);
      float y0 = bs[lane], y1 = bs[64 + lane], y2 = bs[128 + lane];
#pragma unroll
      for (int d = 0; d < 64; ++d) {
        y0 += __shfl(f0, d, 64) * Wg[d * 64 + lane];
        y1 += __shfl(f1, d, 64) * Wg[4096 + d * 64 + lane];
        y2 += __shfl(f2, d, 64) * Wg[8192 + d * 64 + lane];
      }
      float aux1 = f0 * y0, aux2 = f1 * y1, tgt = f2 * y2;
      float sc1 = wave_sum(tgt * ts[lane] + aux1 * ts[64 + lane]);
      float sc2 = wave_sum(tgt * ts[128 + lane] + aux2 * ts[192 + lane]);
      if (lane == 0) {
        storef(out, OFF_S1 + n, sc1, f32);
        storef(out, OFF_S2 + n, sc2, f32);
      }
    } else {
      int ob = OFF_I + (n - N_USERS) * RD + lane;
      storef(out, ob, f0, f32);
      storef(out, ob + 64, f1, f32);
      storef(out, ob + 128, f2, f32);
    }
  }
}

extern "C" void kernel_launch(void* const* d_in, const int* in_sizes, int n_in,
                              void* d_out, int out_size, void* d_ws,
                              size_t ws_size, hipStream_t stream) {
  const void* user_emb = d_in[0];
  const void* item_emb = d_in[1];
  const void* rel_emb = d_in[2];
  const void* W_gc = d_in[3];
  const void* W_rel = d_in[4];
  const void* gru_w = d_in[5];
  const void* gru_b = d_in[6];
  const void* tra = d_in[7];
  const void* adj_vals = d_in[8];
  const int* adj_rows = (const int*)d_in[9];
  const int* adj_cols = (const int*)d_in[10];

  // ws layout: [flag(int) pad to 1024 floats][prop fp32][all_emb fp32][ego bf16]
  int* flag = (int*)d_ws;
  float* wsf = (float*)d_ws;
  float* rela_f = wsf + 16;               // 576 floats
  float* prop = wsf + 1024;
  float* all_emb = prop + (size_t)N_NODES * RD;
  bf16* ego = (bf16*)(all_emb + (size_t)N_NODES * RD);

  detect_kernel<<<1, 256, 0, stream>>>((const unsigned short*)user_emb, flag);
  rela_kernel<<<1, 192, 0, stream>>>(rel_emb, W_rel, flag, rela_f, d_out);
  zero_row_kernel<<<1, 192, 0, stream>>>(d_out, flag);
  init_kernel<<<(N_NODES * RD + 255) / 256, 256, 0, stream>>>(
      user_emb, item_emb, flag, ego, all_emb);
  for (int k = 0; k < 2; ++k) {
    (void)hipMemsetAsync(prop, 0, (size_t)N_NODES * RD * sizeof(float), stream);
    scatter_kernel<<<dim3(EE / 4, 3), 256, 0, stream>>>(
        ego, adj_vals, adj_rows, adj_cols, flag, prop);
    transform_attn_kernel<<<N_NODES / 32, 256, 0, stream>>>(
        prop, rela_f + k * 192, W_gc, k * 4096, flag, ego, all_emb);
  }
  final_kernel<<<(N_NODES + 63) / 64, 256, 0, stream>>>(
      all_emb, gru_w, gru_b, tra, flag, d_out);
}